// Round 6
// baseline (988.000 us; speedup 1.0000x reference)
//
#include <hip/hip_runtime.h>

// Problem constants
#define B_SZ   64
#define S_LEN  200
#define H_DIM  1024
#define NHEAD  16
#define HDIM   64
#define FF_DIM 4096
#define NROWS  (B_SZ * S_LEN)   // 12800

typedef __bf16 bf16x8 __attribute__((ext_vector_type(8)));
typedef float  f32x4  __attribute__((ext_vector_type(4)));

#define GLOBAL_AS __attribute__((address_space(1)))
#define LDS_AS    __attribute__((address_space(3)))

__device__ __forceinline__ void g2lds16(const void* g, void* l) {
  __builtin_amdgcn_global_load_lds((const GLOBAL_AS void*)g, (LDS_AS void*)l, 16, 0, 0);
}

__device__ __forceinline__ float b2f(ushort u) {
  return __uint_as_float(((unsigned int)u) << 16);
}
__device__ __forceinline__ ushort f2b(float f) {
  unsigned int u = __float_as_uint(f);
  u += 0x7fffu + ((u >> 16) & 1u);   // RNE
  return (ushort)(u >> 16);
}
__device__ __forceinline__ bf16x8 ld_g16(const ushort* p) {   // 16B global load
  union { uint4 u; bf16x8 v; } r; r.u = *(const uint4*)p; return r.v;
}
__device__ __forceinline__ bf16x8 ld_lds8x2(const ushort* p) { // 2x ds_read_b64
  union { uint2 u[2]; bf16x8 v; } r;
  r.u[0] = *(const uint2*)p;
  r.u[1] = *(const uint2*)(p + 4);
  return r.v;
}

// ---------------------------------------------------------------------------
// prep kernel: all weight transposes (fp32 [K,N] -> bf16 [N,K]) + bias concat
// + pos slice + LN1(+time).  One dispatch, role by blockIdx.x range.
//   [0,1024)      wq   [1024,2048) wk   [2048,3072) wv   [3072,4096) wo
//   [4096,8192)   w1 (128x32)      [8192,12288) w2 (32x128)
//   12288 bias    12289 pos        [12290, 25090) LN1 rows
// ---------------------------------------------------------------------------
struct PrepArgs {
  const float *wq, *wk, *wv, *wo, *w1, *w2;
  ushort *wqkv_t, *wo_t, *w1_t, *w2_t;
  const float *bq, *bk, *bv; float* bqkv;
  const float *pos; ushort* pos_bf;
  const float *x, *g1, *be1, *timev, *wt, *bt; ushort* hbf;
};

__device__ __forceinline__ void transpose_body(
    const float* __restrict__ w, ushort* __restrict__ wt, int K, int N,
    int bx, int by, int t, float (*tile)[33]) {
  int tx = t & 31, ty = t >> 5;   // 32 x 8
  int nb = bx * 32, kb = by * 32;
#pragma unroll
  for (int i = 0; i < 4; ++i)
    tile[ty + i * 8][tx] = w[(size_t)(kb + ty + i * 8) * N + nb + tx];
  __syncthreads();
#pragma unroll
  for (int i = 0; i < 4; ++i)
    wt[(size_t)(nb + ty + i * 8) * K + kb + tx] = f2b(tile[tx][ty + i * 8]);
}

__global__ __launch_bounds__(256) void prep_kernel(PrepArgs a) {
  __shared__ float tile[32][33];
  __shared__ float red[8];
  int id = blockIdx.x, t = threadIdx.x;
  if (id < 1024) {
    transpose_body(a.wq, a.wqkv_t, 1024, 1024, id & 31, id >> 5, t, tile);
  } else if (id < 2048) {
    int i2 = id - 1024;
    transpose_body(a.wk, a.wqkv_t + 1024 * 1024, 1024, 1024, i2 & 31, i2 >> 5, t, tile);
  } else if (id < 3072) {
    int i2 = id - 2048;
    transpose_body(a.wv, a.wqkv_t + 2048 * 1024, 1024, 1024, i2 & 31, i2 >> 5, t, tile);
  } else if (id < 4096) {
    int i2 = id - 3072;
    transpose_body(a.wo, a.wo_t, 1024, 1024, i2 & 31, i2 >> 5, t, tile);
  } else if (id < 8192) {
    int i2 = id - 4096;
    transpose_body(a.w1, a.w1_t, 1024, 4096, i2 & 127, i2 >> 7, t, tile);
  } else if (id < 12288) {
    int i2 = id - 8192;
    transpose_body(a.w2, a.w2_t, 4096, 1024, i2 & 31, i2 >> 5, t, tile);
  } else if (id == 12288) {
    for (int j = t; j < 3072; j += 256)
      a.bqkv[j] = (j < 1024) ? a.bq[j] : (j < 2048 ? a.bk[j - 1024] : a.bv[j - 2048]);
  } else if (id == 12289) {
    for (int j = t; j < 12800; j += 256)
      a.pos_bf[j] = f2b(a.pos[(size_t)199 * 64 + j]);
  } else {
    // LN1 + time embed
    int r = id - 12290;
    const float4* xr = (const float4*)(a.x + (size_t)r * H_DIM);
    float4 xv = xr[t];
    float s  = xv.x + xv.y + xv.z + xv.w;
    float s2 = xv.x * xv.x + xv.y * xv.y + xv.z * xv.z + xv.w * xv.w;
#pragma unroll
    for (int off = 32; off; off >>= 1) {
      s  += __shfl_xor(s, off);
      s2 += __shfl_xor(s2, off);
    }
    int lane = t & 63, wid = t >> 6;
    if (lane == 0) { red[wid] = s; red[4 + wid] = s2; }
    __syncthreads();
    float S  = red[0] + red[1] + red[2] + red[3];
    float S2 = red[4] + red[5] + red[6] + red[7];
    float m    = S * (1.0f / H_DIM);
    float var  = S2 * (1.0f / H_DIM) - m * m;
    float rstd = rsqrtf(var + 1e-5f);
    float tval = a.timev[r];
    float4 gv  = ((const float4*)a.g1)[t];
    float4 bv  = ((const float4*)a.be1)[t];
    float4 wv  = ((const float4*)a.wt)[t];
    float4 btv = ((const float4*)a.bt)[t];
    ushort4 o;
    o.x = f2b((xv.x - m) * rstd * gv.x + bv.x + tval * wv.x + btv.x);
    o.y = f2b((xv.y - m) * rstd * gv.y + bv.y + tval * wv.y + btv.y);
    o.z = f2b((xv.z - m) * rstd * gv.z + bv.z + tval * wv.z + btv.z);
    o.w = f2b((xv.w - m) * rstd * gv.w + bv.w + tval * wv.w + btv.w);
    ((ushort4*)(a.hbf + (size_t)r * H_DIM))[t] = o;
  }
}

// ---------------------------------------------------------------------------
// LayerNorm (fp32 in) -> bf16 out (LN2, standalone)
// ---------------------------------------------------------------------------
__global__ __launch_bounds__(256) void ln_kernel(
    const float* __restrict__ x, const float* __restrict__ g, const float* __restrict__ be,
    ushort* __restrict__ out) {
  int r = blockIdx.x, t = threadIdx.x;
  const float4* xr = (const float4*)(x + (size_t)r * H_DIM);
  float4 xv = xr[t];
  float s  = xv.x + xv.y + xv.z + xv.w;
  float s2 = xv.x * xv.x + xv.y * xv.y + xv.z * xv.z + xv.w * xv.w;
#pragma unroll
  for (int off = 32; off; off >>= 1) {
    s  += __shfl_xor(s, off);
    s2 += __shfl_xor(s2, off);
  }
  __shared__ float red[8];
  int lane = t & 63, wid = t >> 6;
  if (lane == 0) { red[wid] = s; red[4 + wid] = s2; }
  __syncthreads();
  float S  = red[0] + red[1] + red[2] + red[3];
  float S2 = red[4] + red[5] + red[6] + red[7];
  float m    = S * (1.0f / H_DIM);
  float var  = S2 * (1.0f / H_DIM) - m * m;
  float rstd = rsqrtf(var + 1e-5f);
  float4 gv = ((const float4*)g)[t];
  float4 bv = ((const float4*)be)[t];
  ushort4 o;
  o.x = f2b((xv.x - m) * rstd * gv.x + bv.x);
  o.y = f2b((xv.y - m) * rstd * gv.y + bv.y);
  o.z = f2b((xv.z - m) * rstd * gv.z + bv.z);
  o.w = f2b((xv.w - m) * rstd * gv.w + bv.w);
  ((ushort4*)(out + (size_t)r * H_DIM))[t] = o;
}

// ---------------------------------------------------------------------------
// Async producer-consumer bf16 MFMA GEMM.
// C[M,N] = A[M,K]*Bt[N,K]^T + bias[N] (+epilogue as before).
// 320 threads: waves 0-3 = consumers (2x2, 64x64 each, ds_read+MFMA only,
// NO vmem waits); wave 4 = producer (all global_load_lds DMA, depth-2
// pipelined over a 4-deep ring of BK=32 buffers).  No __syncthreads in the
// K-loop: sync via LDS flags (volatile ds + s_sleep polls, ds atomicAdd).
// s_waitcnt imm encodings (gfx9): 0x4F70=vmcnt(16), 0x0F70=vmcnt(0).
// ---------------------------------------------------------------------------
#define NBUF 4
template <int EPI>
__global__ __launch_bounds__(320) void gemm_async(
    const ushort* __restrict__ A, const ushort* __restrict__ Bt,
    const float* __restrict__ bias, void* __restrict__ Cv,
    const float* __restrict__ resid, int M, int N, int K) {
  __shared__ __align__(16) ushort SB[NBUF][2][128 * 32];   // 64 KB ring
  __shared__ int prodf[NBUF];
  __shared__ int consf[NBUF];
  int t = threadIdx.x;
  int lane = t & 63, wave = t >> 6;
  size_t row0 = (size_t)blockIdx.y * 128;
  size_t col0 = (size_t)blockIdx.x * 128;
  if (t < NBUF) { prodf[t] = -1; consf[t] = 0; }
  __syncthreads();
  const int niter = K >> 5;

  if (wave == 4) {
    // ---- producer ----
    int srow = lane >> 2, scol = (lane & 3) * 8;
    const ushort* gA = A  + (row0 + srow) * K + scol;
    const ushort* gB = Bt + (col0 + srow) * K + scol;
    for (int i = 0; i < niter; ++i) {
      int buf = i & (NBUF - 1);
      int target = 4 * ((i - buf + (NBUF - 1)) >> 2);  // prior uses of this buf
      while (*(volatile int*)&consf[buf] < target) __builtin_amdgcn_s_sleep(1);
      __builtin_amdgcn_sched_barrier(0);
      int ko = i << 5;
      ushort* lA = &SB[buf][0][0];
      ushort* lB = &SB[buf][1][0];
#pragma unroll
      for (int j = 0; j < 8; ++j)
        g2lds16(gA + (size_t)(j * 16) * K + ko, lA + j * 512);
#pragma unroll
      for (int j = 0; j < 8; ++j)
        g2lds16(gB + (size_t)(j * 16) * K + ko, lB + j * 512);
      __builtin_amdgcn_sched_barrier(0);
      if (i >= 1) {  // flag iter i-1 (its 16 DMAs are the oldest outstanding)
        __builtin_amdgcn_s_waitcnt(0x4F70);            // vmcnt(16)
        __builtin_amdgcn_sched_barrier(0);
        *(volatile int*)&prodf[(i - 1) & (NBUF - 1)] = i - 1;
      }
    }
    __builtin_amdgcn_s_waitcnt(0x0F70);                // vmcnt(0)
    __builtin_amdgcn_sched_barrier(0);
    *(volatile int*)&prodf[(niter - 1) & (NBUF - 1)] = niter - 1;
    return;
  }

  // ---- consumers (waves 0-3) ----
  int wm = wave >> 1, wn = wave & 1;
  int r15 = lane & 15, quad = lane >> 4;
  f32x4 acc[4][4] = {};
  for (int i = 0; i < niter; ++i) {
    int buf = i & (NBUF - 1);
    while (*(volatile int*)&prodf[buf] < i) __builtin_amdgcn_s_sleep(1);
    __builtin_amdgcn_sched_barrier(0);
    const ushort* As = &SB[buf][0][0];
    const ushort* Bs = &SB[buf][1][0];
    bf16x8 af[4], bfr[4];
#pragma unroll
    for (int ii = 0; ii < 4; ++ii)
      af[ii] = *(const bf16x8*)&As[(wm * 64 + ii * 16 + r15) * 32 + quad * 8];
#pragma unroll
    for (int j = 0; j < 4; ++j)
      bfr[j] = *(const bf16x8*)&Bs[(wn * 64 + j * 16 + r15) * 32 + quad * 8];
#pragma unroll
    for (int ii = 0; ii < 4; ++ii)
#pragma unroll
      for (int j = 0; j < 4; ++j)
        acc[ii][j] = __builtin_amdgcn_mfma_f32_16x16x32_bf16(af[ii], bfr[j], acc[ii][j], 0, 0, 0);
    __builtin_amdgcn_sched_barrier(0);
    atomicAdd(&consf[buf], 1);   // reads retired (MFMA issue forced lgkm wait)
  }

  int mbase = (int)row0 + wm * 64;
  int nbase = (int)col0 + wn * 64;
#pragma unroll
  for (int i = 0; i < 4; ++i) {
#pragma unroll
    for (int j = 0; j < 4; ++j) {
      int col = nbase + j * 16 + r15;
      float bb = bias[col];
#pragma unroll
      for (int ii = 0; ii < 4; ++ii) {
        int row = mbase + i * 16 + quad * 4 + ii;
        size_t idx = (size_t)row * N + col;
        float v = acc[i][j][ii] + bb;
        if constexpr (EPI == 0) {
          ((ushort*)Cv)[idx] = f2b(v);
        } else if constexpr (EPI == 1) {
          float gl = 0.5f * v * (1.0f + erff(v * 0.70710678118f));
          ((ushort*)Cv)[idx] = f2b(gl);
        } else {
          ((float*)Cv)[idx] = v + resid[idx];
        }
      }
    }
  }
}

// ---------------------------------------------------------------------------
// MFMA attention.  One block (4 waves) per (b,h).   (unchanged)
// scores = (Q@K^T)*0.125 + T[q, q-k],  T = Q@P^T  (P = pos_bf, rows d=q-k).
// ---------------------------------------------------------------------------
#define PW_STRIDE 228   // elems per row; 456B: 8B-aligned (b64 reads), ~2-way banks
__global__ __launch_bounds__(256) void attn_kernel(
    const ushort* __restrict__ qkv, const ushort* __restrict__ pos_bf,
    ushort* __restrict__ ctx) {
  int bh = blockIdx.x;
  int b = bh >> 4, h = bh & 15;
  __shared__ ushort Vt[64][PW_STRIDE];       // V^T: Vt[d][k]
  __shared__ ushort Pw[4][16][PW_STRIDE];    // per-wave: T strip, then exp(S)
  int t = threadIdx.x, lane = t & 63, wave = t >> 6;
  int r15 = lane & 15, quad = lane >> 4;
  const size_t base = ((size_t)b * S_LEN) * 3072 + (size_t)h * 64;

  for (int i = t; i < 64 * 28; i += 256) Vt[i / 28][200 + (i % 28)] = 0;
  for (int i = t; i < 800; i += 256) {
    int kp = i >> 3, d0 = (i & 7) * 8;
    int k = kp * 2;
    union { uint4 v; ushort u[8]; } r0, r1;
    r0.v = *(const uint4*)&qkv[base + (size_t)k * 3072 + 2048 + d0];
    r1.v = *(const uint4*)&qkv[base + (size_t)(k + 1) * 3072 + 2048 + d0];
#pragma unroll
    for (int j = 0; j < 8; ++j) {
      ushort2 w2; w2.x = r0.u[j]; w2.y = r1.u[j];
      *(ushort2*)&Vt[d0 + j][k] = w2;
    }
  }
  __syncthreads();

  for (int qt = wave; qt < 13; qt += 4) {
    int q0 = qt * 16;
    int qrow = q0 + r15; if (qrow > 199) qrow = 199;
    const ushort* qp = qkv + base + (size_t)qrow * 3072;
    bf16x8 aq0 = ld_g16(qp + quad * 8);
    bf16x8 aq1 = ld_g16(qp + 32 + quad * 8);
    ushort* pw = &Pw[wave][0][0];

#pragma unroll
    for (int dt = 0; dt < 13; ++dt) {
      if (dt > qt) continue;
      int prow = dt * 16 + r15; if (prow > 199) prow = 199;
      const ushort* pp = pos_bf + (size_t)prow * 64;
      bf16x8 p0 = ld_g16(pp + quad * 8);
      bf16x8 p1 = ld_g16(pp + 32 + quad * 8);
      f32x4 tt = {};
      tt = __builtin_amdgcn_mfma_f32_16x16x32_bf16(aq0, p0, tt, 0, 0, 0);
      tt = __builtin_amdgcn_mfma_f32_16x16x32_bf16(aq1, p1, tt, 0, 0, 0);
#pragma unroll
      for (int ii = 0; ii < 4; ++ii)
        pw[(quad * 4 + ii) * PW_STRIDE + dt * 16 + r15] = f2b(tt[ii]);
    }

    f32x4 sreg[13];
    float rowmax[4] = {-3.0e38f, -3.0e38f, -3.0e38f, -3.0e38f};
#pragma unroll
    for (int kt = 0; kt < 13; ++kt) {
      if (kt > qt) continue;
      int krow = kt * 16 + r15; if (krow > 199) krow = 199;
      const ushort* kp = qkv + base + (size_t)krow * 3072 + 1024;
      bf16x8 k0 = ld_g16(kp + quad * 8);
      bf16x8 k1 = ld_g16(kp + 32 + quad * 8);
      f32x4 s = {};
      s = __builtin_amdgcn_mfma_f32_16x16x32_bf16(aq0, k0, s, 0, 0, 0);
      s = __builtin_amdgcn_mfma_f32_16x16x32_bf16(aq1, k1, s, 0, 0, 0);
      int k = kt * 16 + r15;
#pragma unroll
      for (int ii = 0; ii < 4; ++ii) {
        int q = q0 + quad * 4 + ii;
        float v;
        if (k <= q) {
          v = s[ii] * 0.125f + b2f(pw[(quad * 4 + ii) * PW_STRIDE + (q - k)]);
        } else {
          v = -1.0e30f;
        }
        s[ii] = v;
        rowmax[ii] = fmaxf(rowmax[ii], v);
      }
      sreg[kt] = s;
    }
#pragma unroll
    for (int off = 8; off; off >>= 1)
#pragma unroll
      for (int ii = 0; ii < 4; ++ii)
        rowmax[ii] = fmaxf(rowmax[ii], __shfl_xor(rowmax[ii], off));

    float rsum[4] = {0.f, 0.f, 0.f, 0.f};
#pragma unroll
    for (int kt = 0; kt < 13; ++kt) {
      if (kt > qt) continue;
#pragma unroll
      for (int ii = 0; ii < 4; ++ii) {
        float e = __expf(sreg[kt][ii] - rowmax[ii]);
        rsum[ii] += e;
        pw[(quad * 4 + ii) * PW_STRIDE + kt * 16 + r15] = f2b(e);
      }
    }
    if ((qt & 1) == 0) {
#pragma unroll
      for (int ii = 0; ii < 4; ++ii)
        pw[(quad * 4 + ii) * PW_STRIDE + (qt + 1) * 16 + r15] = 0;
    }
#pragma unroll
    for (int off = 8; off; off >>= 1)
#pragma unroll
      for (int ii = 0; ii < 4; ++ii)
        rsum[ii] += __shfl_xor(rsum[ii], off);
    float rinv[4];
#pragma unroll
    for (int ii = 0; ii < 4; ++ii) rinv[ii] = 1.0f / rsum[ii];

    int nk = (q0 + 15) / 32 + 1;
    f32x4 acc[4] = {};
#pragma unroll
    for (int k32 = 0; k32 < 7; ++k32) {
      if (k32 >= nk) continue;
      bf16x8 ap = ld_lds8x2(&pw[r15 * PW_STRIDE + k32 * 32 + quad * 8]);
#pragma unroll
      for (int n = 0; n < 4; ++n) {
        bf16x8 bv = ld_lds8x2(&Vt[n * 16 + r15][k32 * 32 + quad * 8]);
        acc[n] = __builtin_amdgcn_mfma_f32_16x16x32_bf16(ap, bv, acc[n], 0, 0, 0);
      }
    }
#pragma unroll
    for (int n = 0; n < 4; ++n)
#pragma unroll
      for (int ii = 0; ii < 4; ++ii) {
        int q = q0 + quad * 4 + ii;
        if (q < S_LEN)
          ctx[((size_t)(b * S_LEN + q)) * H_DIM + h * 64 + n * 16 + r15] =
              f2b(acc[n][ii] * rinv[ii]);
      }
  }
}

// ---------------------------------------------------------------------------
// Launcher.  Workspace layout (aliased; peak ~124 MB):
//   [weights bf16^T: 25.2 MB][pos_bf 25.6KB][qkv 78.6 MB -> h2+gelu chunk]
//   [hbf 26.2 MB -> ctx]          res2 lives in d_out (fp32, 52.4 MB).
// ---------------------------------------------------------------------------
extern "C" void kernel_launch(void* const* d_in, const int* in_sizes, int n_in,
                              void* d_out, int out_size, void* d_ws, size_t ws_size,
                              hipStream_t stream) {
  (void)in_sizes; (void)n_in; (void)out_size; (void)ws_size;
  const float* x    = (const float*)d_in[0];
  const float* timev= (const float*)d_in[1];
  const float* wq   = (const float*)d_in[2];
  const float* bq   = (const float*)d_in[3];
  const float* wk   = (const float*)d_in[4];
  const float* bk   = (const float*)d_in[5];
  const float* wv   = (const float*)d_in[6];
  const float* bv   = (const float*)d_in[7];
  const float* wo   = (const float*)d_in[8];
  const float* bo   = (const float*)d_in[9];
  const float* wt   = (const float*)d_in[10];
  const float* bt   = (const float*)d_in[11];
  const float* pos  = (const float*)d_in[12];
  const float* g1   = (const float*)d_in[13];
  const float* be1  = (const float*)d_in[14];
  const float* g2   = (const float*)d_in[15];
  const float* be2  = (const float*)d_in[16];
  const float* w1   = (const float*)d_in[17];
  const float* bf1  = (const float*)d_in[18];
  const float* w2   = (const float*)d_in[19];
  const float* bf2  = (const float*)d_in[20];

  char* ws = (char*)d_ws;
  ushort* wqkv_t = (ushort*)ws;   ws += (size_t)3072 * 1024 * 2;   //  6.29 MB
  ushort* wo_t   = (ushort*)ws;   ws += (size_t)1024 * 1024 * 2;   //  2.10 MB
  ushort* w1_t   = (ushort*)ws;   ws += (size_t)4096 * 1024 * 2;   //  8.39 MB
  ushort* w2_t   = (ushort*)ws;   ws += (size_t)1024 * 4096 * 2;   //  8.39 MB
  float*  bqkv   = (float*)ws;    ws += (size_t)16384;             //  16 KB
  ushort* pos_bf = (ushort*)ws;   ws += (size_t)200 * 64 * 2;      //  25.6 KB
  char* r1 = ws;                  ws += (size_t)NROWS * 3072 * 2;  // 78.64 MB
  ushort* qkv  = (ushort*)r1;
  ushort* h2   = (ushort*)r1;                                      // 26.21 MB
  ushort* gbuf = (ushort*)(r1 + (size_t)NROWS * H_DIM * 2);        // 52.43 MB
  char* r2 = ws;                  ws += (size_t)NROWS * 1024 * 2;  // 26.21 MB
  ushort* hbf = (ushort*)r2;
  ushort* ctx = (ushort*)r2;
  float* res2 = (float*)d_out;

  // one prep dispatch: 6 transposes + bias concat + pos slice + LN1
  PrepArgs pa;
  pa.wq = wq; pa.wk = wk; pa.wv = wv; pa.wo = wo; pa.w1 = w1; pa.w2 = w2;
  pa.wqkv_t = wqkv_t; pa.wo_t = wo_t; pa.w1_t = w1_t; pa.w2_t = w2_t;
  pa.bq = bq; pa.bk = bk; pa.bv = bv; pa.bqkv = bqkv;
  pa.pos = pos; pa.pos_bf = pos_bf;
  pa.x = x; pa.g1 = g1; pa.be1 = be1; pa.timev = timev; pa.wt = wt; pa.bt = bt;
  pa.hbf = hbf;
  prep_kernel<<<12290 + NROWS, 256, 0, stream>>>(pa);

  // fused QKV GEMM: [12800,1024] x [3072,1024]^T -> qkv bf16
  gemm_async<0><<<dim3(24, 100), 320, 0, stream>>>(hbf, wqkv_t, bqkv, qkv, nullptr,
                                                   NROWS, 3072, 1024);
  // MFMA attention: qkv -> ctx (overwrites hbf region; hbf is dead now)
  attn_kernel<<<B_SZ * NHEAD, 256, 0, stream>>>(qkv, pos_bf, ctx);

  // out = ctx @ wo + bo + x   (fp32, into d_out as res2)
  gemm_async<2><<<dim3(8, 100), 320, 0, stream>>>(ctx, wo_t, bo, res2, x,
                                                  NROWS, 1024, 1024);
  // LN2 -> h2 (bf16, overwrites qkv region; qkv is dead now)
  ln_kernel<<<NROWS, 256, 0, stream>>>(res2, g2, be2, h2);

  // FF in 2 row-chunks of 6400 (gelu buffer fits in the freed qkv region)
  for (int c = 0; c < 2; ++c) {
    size_t ro = (size_t)c * 6400;
    gemm_async<1><<<dim3(32, 50), 320, 0, stream>>>(h2 + ro * 1024, w1_t, bf1, gbuf, nullptr,
                                                    6400, 4096, 1024);
    gemm_async<2><<<dim3(8, 50), 320, 0, stream>>>(gbuf, w2_t, bf2, (float*)d_out + ro * 1024,
                                                   res2 + ro * 1024, 6400, 1024, 4096);
  }
}